// Round 7
// baseline (114.755 us; speedup 1.0000x reference)
//
#include <hip/hip_runtime.h>
#include <math.h>

// PointsGeneration: elementwise sigmoid + threshold-gated regression concat.
//
// R6 = R4 (8 KB runs per stream visit, 2048 waves = 2 waves/SIMD — the
// measured locality/occupancy sweet spot) + PAIRED-CHANNEL phase 2: process
// regression channels two at a time so the MC sees {16 loads, 16 stores}
// batches instead of {8,8} — halves DRAM read/write bus turnarounds in the
// phase carrying 12/16 of the output traffic.
// R5 post-mortem: 16 KB runs @ 1 wave/SIMD regressed (113.5 vs 107.5) —
// single resident wave can't overlap its own load->compute->store chain.

typedef float f32x4 __attribute__((ext_vector_type(4)));

static __device__ __forceinline__ float sigf(float x) {
    // Accurate fp32 sigmoid (expf, not __expf): threshold comparisons sit on
    // the sigmoid value; match the numpy fp32 reference to avoid mask flips.
    return 1.0f / (1.0f + expf(-x));
}

static __device__ __forceinline__ f32x4 ld4(const float* p) {
    return *reinterpret_cast<const f32x4*>(p);
}
static __device__ __forceinline__ void st4(float* p, f32x4 v) {
    *reinterpret_cast<f32x4*>(p) = v;
}

// Gate a PAIR of regression channels' 8 KB windows by mask m (batched
// {16 loads, 16 stores} to halve R/W turnarounds).
static __device__ __forceinline__ void reg_pair(
    const float* __restrict__ srcA, float* __restrict__ dstA,
    const float* __restrict__ srcB, float* __restrict__ dstB,
    unsigned m, int base)
{
    f32x4 a[8], b[8];
#pragma unroll
    for (int j = 0; j < 8; ++j) a[j] = ld4(srcA + base + j * 256);
#pragma unroll
    for (int j = 0; j < 8; ++j) b[j] = ld4(srcB + base + j * 256);
#pragma unroll
    for (int j = 0; j < 8; ++j) {
#pragma unroll
        for (int k = 0; k < 4; ++k) {
            const bool on = (m >> (4 * j + k)) & 1u;
            a[j][k] = on ? a[j][k] : 0.0f;
            b[j][k] = on ? b[j][k] : 0.0f;
        }
    }
#pragma unroll
    for (int j = 0; j < 8; ++j) st4(dstA + base + j * 256, a[j]);
#pragma unroll
    for (int j = 0; j < 8; ++j) st4(dstB + base + j * 256, b[j]);
}

__global__ __launch_bounds__(256) void points_gen_kernel(
    const float* __restrict__ p_text,
    const float* __restrict__ p_head,
    const float* __restrict__ p_tail,
    const float* __restrict__ p_bond,
    const float* __restrict__ p_rh,
    const float* __restrict__ p_rt,
    const float* __restrict__ p_rb,
    float* __restrict__ out)
{
    constexpr int N = 2048 * 2048;   // pixels per plane
    constexpr int WPX = 2048;        // pixels per wave per plane (8 KB)
    const int lane = threadIdx.x & 63;
    const int wave = (blockIdx.x * blockDim.x + threadIdx.x) >> 6;  // 0..2047
    const int base = wave * WPX + lane * 4;   // + j*256 for j in 0..7

    // ---- phase 1: score planes (batched: 32 loads, then 32 stores) ----
    f32x4 T[8], H[8], L[8], B[8];
#pragma unroll
    for (int j = 0; j < 8; ++j) T[j] = ld4(p_text + base + j * 256);
#pragma unroll
    for (int j = 0; j < 8; ++j) H[j] = ld4(p_head + base + j * 256);
#pragma unroll
    for (int j = 0; j < 8; ++j) L[j] = ld4(p_tail + base + j * 256);
#pragma unroll
    for (int j = 0; j < 8; ++j) B[j] = ld4(p_bond + base + j * 256);

    unsigned mt = 0, mh = 0, ml = 0, mb = 0;  // 32 pixel-bits each
#pragma unroll
    for (int j = 0; j < 8; ++j) {
#pragma unroll
        for (int k = 0; k < 4; ++k) {
            T[j][k] = sigf(T[j][k]);
            if (T[j][k] > 0.45f) mt |= 1u << (4 * j + k);
            H[j][k] = sigf(H[j][k]);
            if (H[j][k] > 0.5f) mh |= 1u << (4 * j + k);
            L[j][k] = sigf(L[j][k]);
            if (L[j][k] > 0.5f) ml |= 1u << (4 * j + k);
            B[j][k] = sigf(B[j][k]);
            if (B[j][k] > 0.5f) mb |= 1u << (4 * j + k);
        }
    }

#pragma unroll
    for (int j = 0; j < 8; ++j) st4(out + 0 * N + base + j * 256, T[j]);
#pragma unroll
    for (int j = 0; j < 8; ++j) st4(out + 1 * N + base + j * 256, H[j]);
#pragma unroll
    for (int j = 0; j < 8; ++j) st4(out + 2 * N + base + j * 256, L[j]);
#pragma unroll
    for (int j = 0; j < 8; ++j) st4(out + 3 * N + base + j * 256, B[j]);

    mh &= mt;   // head mask = text & head
    ml &= mt;   // tail mask = text & tail

    // ---- phase 2: gated regression channels, two streams per batch ----
    reg_pair(p_rh + 0 * N, out + 4 * N,  p_rh + 1 * N, out + 5 * N,  mh, base);
    reg_pair(p_rh + 2 * N, out + 6 * N,  p_rh + 3 * N, out + 7 * N,  mh, base);
    reg_pair(p_rt + 0 * N, out + 8 * N,  p_rt + 1 * N, out + 9 * N,  ml, base);
    reg_pair(p_rt + 2 * N, out + 10 * N, p_rt + 3 * N, out + 11 * N, ml, base);
    reg_pair(p_rb + 0 * N, out + 12 * N, p_rb + 1 * N, out + 13 * N, mb, base);
    reg_pair(p_rb + 2 * N, out + 14 * N, p_rb + 3 * N, out + 15 * N, mb, base);
}

extern "C" void kernel_launch(void* const* d_in, const int* in_sizes, int n_in,
                              void* d_out, int out_size, void* d_ws, size_t ws_size,
                              hipStream_t stream) {
    (void)in_sizes; (void)n_in; (void)out_size; (void)d_ws; (void)ws_size;

    const float* p_text = (const float*)d_in[0];
    const float* p_head = (const float*)d_in[1];
    const float* p_tail = (const float*)d_in[2];
    const float* p_bond = (const float*)d_in[3];
    const float* p_rh   = (const float*)d_in[4];
    const float* p_rt   = (const float*)d_in[5];
    const float* p_rb   = (const float*)d_in[6];
    float* out = (float*)d_out;

    constexpr int N = 2048 * 2048;
    constexpr int WPX = 2048;                       // pixels per wave per plane
    constexpr int waves = N / WPX;                  // 2048
    constexpr int threads = 256;                    // 4 waves per block
    constexpr int blocks = waves * 64 / threads;    // 512

    points_gen_kernel<<<blocks, threads, 0, stream>>>(
        p_text, p_head, p_tail, p_bond, p_rh, p_rt, p_rb, out);
}

// Round 8
// 106.257 us; speedup vs baseline: 1.0800x; 1.0800x over previous
//
#include <hip/hip_runtime.h>
#include <math.h>

// PointsGeneration: elementwise sigmoid + threshold-gated regression concat.
//
// R7: decouple occupancy from run length. 4 wave-groups (g = waveId & 3):
//   g0: 4 score planes -> sigmoid -> ch 0..3
//   g1: text+head masks -> gate reg_head -> ch 4..7
//   g2: text+tail masks -> gate reg_tail -> ch 8..11
//   g3: bond mask -> gate reg_bond -> ch 12..15
// Every stream visit stays an 8 KB contiguous run (R4's measured sweet
// spot), planes processed sequentially (<=8 f32x4 live, VGPR ~50) so the
// grid's 8192 waves reach 8 waves/SIMD (vs R4's 2). Same-window groups
// share a block: g1/g2 re-reads of score planes are L1/L2-hot behind g0.
// Ledger: 1KB=120, 8KB@2w=107.5 (R4 best), 16KB@1w=113.5, pair-batch=114.8.

typedef float f32x4 __attribute__((ext_vector_type(4)));

static __device__ __forceinline__ float sigf(float x) {
    // Accurate fp32 sigmoid (expf, not __expf): threshold comparisons sit on
    // the sigmoid value; match the numpy fp32 reference to avoid mask flips.
    return 1.0f / (1.0f + expf(-x));
}

static __device__ __forceinline__ f32x4 ld4(const float* p) {
    return *reinterpret_cast<const f32x4*>(p);
}
static __device__ __forceinline__ void st4(float* p, f32x4 v) {
    *reinterpret_cast<f32x4*>(p) = v;
}

// sigmoid(plane window) -> store (8 KB run in, 8 KB run out)
static __device__ __forceinline__ void plane_sig(
    const float* __restrict__ src, float* __restrict__ dst, int base)
{
    f32x4 v[8];
#pragma unroll
    for (int j = 0; j < 8; ++j) v[j] = ld4(src + base + j * 256);
#pragma unroll
    for (int j = 0; j < 8; ++j)
#pragma unroll
        for (int k = 0; k < 4; ++k) v[j][k] = sigf(v[j][k]);
#pragma unroll
    for (int j = 0; j < 8; ++j) st4(dst + base + j * 256, v[j]);
}

// 32-bit mask of (sigmoid(window) > thr), values discarded
static __device__ __forceinline__ unsigned mask_of(
    const float* __restrict__ src, float thr, int base)
{
    f32x4 v[8];
#pragma unroll
    for (int j = 0; j < 8; ++j) v[j] = ld4(src + base + j * 256);
    unsigned m = 0;
#pragma unroll
    for (int j = 0; j < 8; ++j)
#pragma unroll
        for (int k = 0; k < 4; ++k)
            if (sigf(v[j][k]) > thr) m |= 1u << (4 * j + k);
    return m;
}

// gate one regression channel window by mask (8 KB run in, 8 KB run out)
static __device__ __forceinline__ void gate(
    const float* __restrict__ src, float* __restrict__ dst,
    unsigned m, int base)
{
    f32x4 v[8];
#pragma unroll
    for (int j = 0; j < 8; ++j) v[j] = ld4(src + base + j * 256);
#pragma unroll
    for (int j = 0; j < 8; ++j)
#pragma unroll
        for (int k = 0; k < 4; ++k)
            v[j][k] = ((m >> (4 * j + k)) & 1u) ? v[j][k] : 0.0f;
#pragma unroll
    for (int j = 0; j < 8; ++j) st4(dst + base + j * 256, v[j]);
}

__global__ __launch_bounds__(256) void points_gen_kernel(
    const float* __restrict__ p_text,
    const float* __restrict__ p_head,
    const float* __restrict__ p_tail,
    const float* __restrict__ p_bond,
    const float* __restrict__ p_rh,
    const float* __restrict__ p_rt,
    const float* __restrict__ p_rb,
    float* __restrict__ out)
{
    constexpr int N = 2048 * 2048;   // pixels per plane
    constexpr int WPX = 2048;        // pixels per wave per plane (8 KB)
    const int lane = threadIdx.x & 63;
    const int gwave = blockIdx.x * 4 + (threadIdx.x >> 6);  // 0..8191
    const int g = gwave & 3;         // group; same window's 4 groups share a block
    const int w = gwave >> 2;        // window index 0..2047
    const int base = w * WPX + lane * 4;   // + j*256 for j in 0..7

    if (g == 0) {
        plane_sig(p_text, out + 0 * N, base);
        plane_sig(p_head, out + 1 * N, base);
        plane_sig(p_tail, out + 2 * N, base);
        plane_sig(p_bond, out + 3 * N, base);
    } else if (g == 1) {
        const unsigned m = mask_of(p_text, 0.45f, base) &
                           mask_of(p_head, 0.50f, base);
#pragma unroll
        for (int c = 0; c < 4; ++c)
            gate(p_rh + c * N, out + (4 + c) * N, m, base);
    } else if (g == 2) {
        const unsigned m = mask_of(p_text, 0.45f, base) &
                           mask_of(p_tail, 0.50f, base);
#pragma unroll
        for (int c = 0; c < 4; ++c)
            gate(p_rt + c * N, out + (8 + c) * N, m, base);
    } else {
        const unsigned m = mask_of(p_bond, 0.50f, base);
#pragma unroll
        for (int c = 0; c < 4; ++c)
            gate(p_rb + c * N, out + (12 + c) * N, m, base);
    }
}

extern "C" void kernel_launch(void* const* d_in, const int* in_sizes, int n_in,
                              void* d_out, int out_size, void* d_ws, size_t ws_size,
                              hipStream_t stream) {
    (void)in_sizes; (void)n_in; (void)out_size; (void)d_ws; (void)ws_size;

    const float* p_text = (const float*)d_in[0];
    const float* p_head = (const float*)d_in[1];
    const float* p_tail = (const float*)d_in[2];
    const float* p_bond = (const float*)d_in[3];
    const float* p_rh   = (const float*)d_in[4];
    const float* p_rt   = (const float*)d_in[5];
    const float* p_rb   = (const float*)d_in[6];
    float* out = (float*)d_out;

    constexpr int N = 2048 * 2048;
    constexpr int WPX = 2048;                        // pixels per wave per plane
    constexpr int windows = N / WPX;                 // 2048
    constexpr int waves = windows * 4;               // 8192 (4 groups)
    constexpr int blocks = waves / 4;                // 2048 blocks x 4 waves

    points_gen_kernel<<<blocks, 256, 0, stream>>>(
        p_text, p_head, p_tail, p_bond, p_rh, p_rt, p_rb, out);
}